// Round 7
// baseline (444.462 us; speedup 1.0000x reference)
//
#include <hip/hip_runtime.h>
#include <stdint.h>

typedef __attribute__((ext_vector_type(8))) short short8;     // 8 x bf16 MFMA operand
typedef __attribute__((ext_vector_type(4))) float floatx4;    // 16x16 MFMA accumulator
typedef __attribute__((ext_vector_type(16))) float floatx16;  // 32x32 MFMA accumulator

#define DEV __device__ __forceinline__

DEV unsigned short f2bf(float x) {  // fp32 -> bf16 RNE (epilogue-only)
  unsigned u = __float_as_uint(x);
  u += 0x7fffu + ((u >> 16) & 1u);
  return (unsigned short)(u >> 16);
}

// pack two fp32 -> two bf16 (round-half-up) in 3 VALU: 2 adds + v_perm
DEV unsigned pkbf(float hi, float lo) {
  return __builtin_amdgcn_perm(__float_as_uint(hi) + 0x8000u,
                               __float_as_uint(lo) + 0x8000u, 0x07060302u);
}

// single-instruction pack: dst = {lo16: bf16(a), hi16: bf16(b)} (RNE)
DEV unsigned cvtpk(float a, float b) {
  unsigned r;
  asm("v_cvt_pk_bf16_f32 %0, %1, %2" : "=v"(r) : "v"(a), "v"(b));
  return r;
}

DEV short8 pack4(unsigned a0, unsigned a1, unsigned b0, unsigned b1) {
  union { unsigned u[4]; short8 s; } t;
  t.u[0] = a0; t.u[1] = a1; t.u[2] = b0; t.u[3] = b1;
  return t.s;
}

DEV void load_lds16(const unsigned short* g, unsigned short* l) {
  __builtin_amdgcn_global_load_lds(
      (const __attribute__((address_space(1))) void*)g,
      (__attribute__((address_space(3))) void*)l, 16, 0, 0);
}

#define ASM_VMCNT(n) asm volatile("s_waitcnt vmcnt(" #n ")" ::: "memory")
#define ASM_LGKM0() asm volatile("s_waitcnt lgkmcnt(0)" ::: "memory")
DEV void sched_fence() { __builtin_amdgcn_sched_barrier(0); }

// LDS fragment read with 2-way-conflict-free chunk swizzle (slot = quad ^ ((row>>1)&3))
DEV short8 fragld(const unsigned short* buf, int row, int quad) {
  return *(const short8*)(buf + row * 32 + ((quad ^ ((row >> 1) & 3)) * 8));
}

// ---------------- fused QKV projection: fp32 in, fused cvt, reg-staged, grid (8,64,3) -------
// Per kt: frag reads buf[kt&1] -> 16 MFMA -> cvt+ds_write tile kt+1 (loads issued last iter,
// full-iter latency hiding) -> issue fp32 loads for kt+2 -> lgkmcnt(0) + raw s_barrier
// (no vmcnt drain: in-flight loads target registers and survive the barrier).
#define SCQ (0.125f * 1.44269504089f)
__global__ __launch_bounds__(256, 3) void qkv_gemm(
    const float* __restrict__ Xq, const float* __restrict__ Xk, const float* __restrict__ Xv,
    const float* __restrict__ Wqw, const float* __restrict__ Wkw, const float* __restrict__ Wvw,
    const float* __restrict__ bq, const float* __restrict__ bk, const float* __restrict__ bv,
    unsigned short* __restrict__ Qp, unsigned short* __restrict__ Kp,
    unsigned short* __restrict__ VTp) {
  __shared__ alignas(16) unsigned short Xs[2][128 * 32];  // 16KB
  __shared__ alignas(16) unsigned short Ws[2][128 * 32];  // 16KB
  const int z = blockIdx.z;
  const float* X = z == 0 ? Xq : z == 1 ? Xk : Xv;
  const float* W = z == 0 ? Wqw : z == 1 ? Wkw : Wvw;
  const float* bias = z == 0 ? bq : z == 1 ? bk : bv;

  const int tid = threadIdx.x;
  const int lane = tid & 63, wave = tid >> 6;
  const int lcol = lane & 15, quad = lane >> 4;
  // XCD L2-locality remap (R3): xcd owns a contiguous 8-block s-span
  const int n2 = blockIdx.x + 8 * blockIdx.y;
  const int xcd = n2 & 7, ii = n2 >> 3;
  const int wo = (ii >> 3) * 128;
  const int xo = (xcd * 8 + (ii & 7)) * 128;
  const int wm = (wave & 1) * 64;
  const int wn = (wave >> 1) * 64;

  // staging mapping: thread -> (row, half); 16 contiguous f32 per tensor per tile
  const int srow = tid >> 1, half = tid & 1;
  const float* Xrow = X + (size_t)(xo + srow) * 1024 + half * 16;
  const float* Wrow = W + (size_t)(wo + srow) * 1024 + half * 16;
  const int ssw = (srow >> 1) & 3;  // chunk swizzle for this row

  float4 rx[4], rw[4];  // in-flight fp32 tile fragments (32 VGPR)
  auto issue = [&](int kt) {
    const int k0 = kt * 32;
#pragma unroll
    for (int j = 0; j < 4; ++j) {
      rx[j] = *(const float4*)(Xrow + k0 + j * 4);
      rw[j] = *(const float4*)(Wrow + k0 + j * 4);
    }
  };
  auto writeT = [&](int buf) {  // cvt 32 f32 -> 32 bf16, 4x ds_write_b128 (chunk-swizzled)
#pragma unroll
    for (int e = 0; e < 2; ++e) {
      int ch = half * 2 + e;
      unsigned x0 = cvtpk(rx[2 * e].x, rx[2 * e].y);
      unsigned x1 = cvtpk(rx[2 * e].z, rx[2 * e].w);
      unsigned x2 = cvtpk(rx[2 * e + 1].x, rx[2 * e + 1].y);
      unsigned x3 = cvtpk(rx[2 * e + 1].z, rx[2 * e + 1].w);
      *(short8*)(Xs[buf] + srow * 32 + ((ch ^ ssw) * 8)) = pack4(x0, x1, x2, x3);
      unsigned w0 = cvtpk(rw[2 * e].x, rw[2 * e].y);
      unsigned w1 = cvtpk(rw[2 * e].z, rw[2 * e].w);
      unsigned w2 = cvtpk(rw[2 * e + 1].x, rw[2 * e + 1].y);
      unsigned w3 = cvtpk(rw[2 * e + 1].z, rw[2 * e + 1].w);
      *(short8*)(Ws[buf] + srow * 32 + ((ch ^ ssw) * 8)) = pack4(w0, w1, w2, w3);
    }
  };

  floatx4 acc[4][4];
  for (int mi = 0; mi < 4; ++mi)
    for (int ni = 0; ni < 4; ++ni)
      for (int r = 0; r < 4; ++r) acc[mi][ni][r] = 0.f;

  // prologue: tile 0 staged, tile 1 in flight
  issue(0);
  writeT(0);   // compiler inserts vmcnt for rx/rw
  issue(1);
  ASM_LGKM0();
  sched_fence();
  __builtin_amdgcn_s_barrier();
  sched_fence();

  for (int kt = 0; kt < 32; ++kt) {
    const int cur = kt & 1;
    const unsigned short* Ab = (z < 2) ? Ws[cur] : Xs[cur];
    const unsigned short* Bb = (z < 2) ? Xs[cur] : Ws[cur];
    short8 af[4], bfr[4];
#pragma unroll
    for (int mi = 0; mi < 4; ++mi) af[mi] = fragld(Ab, wm + mi * 16 + lcol, quad);
#pragma unroll
    for (int ni = 0; ni < 4; ++ni) bfr[ni] = fragld(Bb, wn + ni * 16 + lcol, quad);
#pragma unroll
    for (int mi = 0; mi < 4; ++mi)
#pragma unroll
      for (int ni = 0; ni < 4; ++ni)
        acc[mi][ni] = __builtin_amdgcn_mfma_f32_16x16x32_bf16(af[mi], bfr[ni], acc[mi][ni], 0, 0, 0);
    writeT(cur ^ 1);          // tile kt+1 (loads issued last iter; full-iter hiding)
    issue((kt + 2) & 31);     // wrap-issue: harmless garbage at tail, nothing reads it
    ASM_LGKM0();              // ds_writes visible
    sched_fence();
    __builtin_amdgcn_s_barrier();
    sched_fence();
  }

  if (z < 2) {  // lane: d = wo+wm+mi*16+quad*4 (consecutive), s = xo+wn+ni*16+lcol
    unsigned short* Out = z == 0 ? Qp : Kp;
    const float scl = z == 0 ? SCQ : 1.f;
#pragma unroll
    for (int mi = 0; mi < 4; ++mi) {
      int dbase = wo + wm + mi * 16 + quad * 4;
      float4 bv4 = *(const float4*)(bias + dbase);
      int h = dbase >> 6, dk = dbase & 63;
#pragma unroll
      for (int ni = 0; ni < 4; ++ni) {
        int sg = xo + wn + ni * 16 + lcol;  // = b*2048 + s
        int bb = sg >> 11, ss = sg & 2047;
        uint2 o;
        o.x = pkbf((acc[mi][ni][1] + bv4.y) * scl, (acc[mi][ni][0] + bv4.x) * scl);
        o.y = pkbf((acc[mi][ni][3] + bv4.w) * scl, (acc[mi][ni][2] + bv4.z) * scl);
        *(uint2*)(Out + ((size_t)(bb * 16 + h) * 2048 + ss) * 64 + dk) = o;
      }
    }
  } else {  // lane: s = xo+wm+mi*16+quad*4 (consecutive), d = wo+wn+ni*16+lcol -> V^T
#pragma unroll
    for (int ni = 0; ni < 4; ++ni) {
      int dg = wo + wn + ni * 16 + lcol;
      float bvx = bias[dg];
      int h = dg >> 6, dk = dg & 63;
#pragma unroll
      for (int mi = 0; mi < 4; ++mi) {
        int sbase = xo + wm + mi * 16 + quad * 4;
        int bb = sbase >> 11, ss = sbase & 2047;
        uint2 o;
        o.x = pkbf(acc[mi][ni][1] + bvx, acc[mi][ni][0] + bvx);
        o.y = pkbf(acc[mi][ni][3] + bvx, acc[mi][ni][2] + bvx);
        *(uint2*)(VTp + ((size_t)(bb * 16 + h) * 64 + dk) * 2048 + ss) = o;
      }
    }
  }
}

// ---------------- final O-projection: Ctx bf16 + Wo fp32 (fused cvt), fp32 out -------------
__global__ __launch_bounds__(256, 3) void gemm_o(
    const unsigned short* __restrict__ A, const float* __restrict__ Wo,
    const float* __restrict__ bias, float* __restrict__ Out) {
  __shared__ alignas(16) unsigned short Cs[2][128 * 32];
  __shared__ alignas(16) unsigned short Wos[2][128 * 32];
  const int tid = threadIdx.x;
  const int lane = tid & 63, wave = tid >> 6;
  const int lcol = lane & 15, quad = lane >> 4;
  const int n2 = blockIdx.x + 8 * blockIdx.y;
  const int xcd = n2 & 7, ii = n2 >> 3;
  const int co = (ii >> 3) * 128;
  const int so = (xcd * 8 + (ii & 7)) * 128;
  const int wm = (wave & 1) * 64;   // over Wo rows (m = output col)
  const int wn = (wave >> 1) * 64;  // over Ctx rows (n = s)

  const int srow = tid >> 1, half = tid & 1;
  const unsigned short* Crow = A + (size_t)(so + srow) * 1024 + half * 16;
  const float* Wrow = Wo + (size_t)(co + srow) * 1024 + half * 16;
  const int ssw = (srow >> 1) & 3;

  uint4 rc[2];
  float4 rw[4];
  auto issue = [&](int kt) {
    const int k0 = kt * 32;
#pragma unroll
    for (int j = 0; j < 2; ++j) rc[j] = *(const uint4*)(Crow + k0 + j * 8);
#pragma unroll
    for (int j = 0; j < 4; ++j) rw[j] = *(const float4*)(Wrow + k0 + j * 4);
  };
  auto writeT = [&](int buf) {
#pragma unroll
    for (int e = 0; e < 2; ++e) {
      int ch = half * 2 + e;
      *(uint4*)(Cs[buf] + srow * 32 + ((ch ^ ssw) * 8)) = rc[e];
      unsigned w0 = cvtpk(rw[2 * e].x, rw[2 * e].y);
      unsigned w1 = cvtpk(rw[2 * e].z, rw[2 * e].w);
      unsigned w2 = cvtpk(rw[2 * e + 1].x, rw[2 * e + 1].y);
      unsigned w3 = cvtpk(rw[2 * e + 1].z, rw[2 * e + 1].w);
      *(short8*)(Wos[buf] + srow * 32 + ((ch ^ ssw) * 8)) = pack4(w0, w1, w2, w3);
    }
  };

  floatx4 acc[4][4];
  for (int mi = 0; mi < 4; ++mi)
    for (int ni = 0; ni < 4; ++ni)
      for (int r = 0; r < 4; ++r) acc[mi][ni][r] = 0.f;

  issue(0);
  writeT(0);
  issue(1);
  ASM_LGKM0();
  sched_fence();
  __builtin_amdgcn_s_barrier();
  sched_fence();

  for (int kt = 0; kt < 32; ++kt) {
    const int cur = kt & 1;
    short8 af[4], bfr[4];
#pragma unroll
    for (int mi = 0; mi < 4; ++mi) af[mi] = fragld(Wos[cur], wm + mi * 16 + lcol, quad);
#pragma unroll
    for (int ni = 0; ni < 4; ++ni) bfr[ni] = fragld(Cs[cur], wn + ni * 16 + lcol, quad);
#pragma unroll
    for (int mi = 0; mi < 4; ++mi)
#pragma unroll
      for (int ni = 0; ni < 4; ++ni)
        acc[mi][ni] = __builtin_amdgcn_mfma_f32_16x16x32_bf16(af[mi], bfr[ni], acc[mi][ni], 0, 0, 0);
    writeT(cur ^ 1);
    issue((kt + 2) & 31);
    ASM_LGKM0();
    sched_fence();
    __builtin_amdgcn_s_barrier();
    sched_fence();
  }
#pragma unroll
  for (int mi = 0; mi < 4; ++mi) {
    int cb = co + wm + mi * 16 + quad * 4;  // 4 consecutive output cols
    float4 bv4 = *(const float4*)(bias + cb);
#pragma unroll
    for (int ni = 0; ni < 4; ++ni) {
      int sg = so + wn + ni * 16 + lcol;
      float4 o;
      o.x = acc[mi][ni][0] + bv4.x;
      o.y = acc[mi][ni][1] + bv4.y;
      o.z = acc[mi][ni][2] + bv4.z;
      o.w = acc[mi][ni][3] + bv4.w;
      *(float4*)(Out + (size_t)sg * 1024 + cb) = o;
    }
  }
}

// ---------------- flash attention, 32x32 MFMA, in-register P (R5 structure) ----------------
// K/V triple-buffered distance-2, 1 barrier/jt with counted vmcnt(4). Micro-opts vs R5:
// hoisted staging offsets; zero-C first MFMA (no per-jt sacc zero fill).
__global__ __launch_bounds__(256, 3) void attn_kernel(
    const unsigned short* __restrict__ Qp, const unsigned short* __restrict__ Kp,
    const unsigned short* __restrict__ VTp, unsigned short* __restrict__ Ctx) {
  __shared__ alignas(16) unsigned short Ks[3][64 * 64];  // K tiles (24KB); reused as O-stage
  __shared__ alignas(16) unsigned short Vt[3][64 * 64];  // V^T tiles (24KB)

  const int tid = threadIdx.x;
  const int lane = tid & 63, wave = tid >> 6;
  const int l31 = lane & 31, hh = lane >> 5;
  const int wq = wave * 32;
  const int n = blockIdx.x + 16 * (blockIdx.y + 16 * blockIdx.z);
  const int xcd = n & 7, ii = n >> 3;
  const int hb = xcd * 8 + (ii & 7);  // = b*16 + h
  const int qt = ii >> 3;
  const size_t bh = (size_t)hb * 2048 * 64;
  const int b = hb >> 4;
  const unsigned short* Qb = Qp + bh + (size_t)qt * 128 * 64;
  const unsigned short* Kb = Kp + bh;
  const unsigned short* VTb = VTp + bh;

  short8 qf[4];
#pragma unroll
  for (int st = 0; st < 4; ++st)
    qf[st] = *(const short8*)(Qb + (wq + l31) * 64 + st * 16 + hh * 8);

  // hoisted staging offsets (loop-invariant address/swizzle arithmetic)
  const int p0 = tid, p1 = tid + 256;
  const int ko0 = (p0 >> 3) * 64 + (((p0 & 7) ^ ((p0 >> 3) & 7)) * 8);
  const int ko1 = (p1 >> 3) * 64 + (((p1 & 7) ^ ((p1 >> 3) & 7)) * 8);
  const int vo0 = (p0 >> 3) * 2048 + (((p0 & 7) ^ ((p0 >> 3) & 7)) * 8);
  const int vo1 = (p1 >> 3) * 2048 + (((p1 & 7) ^ ((p1 >> 3) & 7)) * 8);
  auto stageK = [&](int jt, int buf) {
    load_lds16(Kb + (size_t)jt * 4096 + ko0, Ks[buf] + p0 * 8);
    load_lds16(Kb + (size_t)jt * 4096 + ko1, Ks[buf] + p1 * 8);
  };
  auto stageV = [&](int jt, int buf) {
    load_lds16(VTb + vo0 + jt * 64, Vt[buf] + p0 * 8);
    load_lds16(VTb + vo1 + jt * 64, Vt[buf] + p1 * 8);
  };

  stageK(0, 0); stageV(0, 0);
  stageK(1, 1); stageV(1, 1);
  __syncthreads();  // full drain (incl. Q loads): tiles 0,1 resident

  short8 ones;
#pragma unroll
  for (int j = 0; j < 8; ++j) ones[j] = (short)0x3f80;
  floatx16 z16;
#pragma unroll
  for (int r = 0; r < 16; ++r) z16[r] = 0.f;

  float M = -1e30f;
  floatx16 Oacc[2], OaccL;
#pragma unroll
  for (int r = 0; r < 16; ++r) { Oacc[0][r] = 0.f; Oacc[1][r] = 0.f; OaccL[r] = 0.f; }

  int cur = 0;
  for (int jt = 0; jt < 32; ++jt) {
    int nb = cur + 2; if (nb >= 3) nb -= 3;
    const int jn = (jt + 2) & 31;  // wrap-issue keeps vmcnt uniform (epilogue drains)
    stageK(jn, nb);
    stageV(jn, nb);

    // S^T[k=64][q=32]: first d-step uses loop-invariant zero C (no sacc zero fill)
    const unsigned short* Kc = Ks[cur];
    floatx16 sacc[2];
#pragma unroll
    for (int mk = 0; mk < 2; ++mk) {
      int row = mk * 32 + l31;
      short8 kf = *(const short8*)(Kc + row * 64 + ((hh ^ (row & 7)) * 8));
      sacc[mk] = __builtin_amdgcn_mfma_f32_32x32x16_bf16(kf, qf[0], z16, 0, 0, 0);
    }
#pragma unroll
    for (int st = 1; st < 4; ++st)
#pragma unroll
      for (int mk = 0; mk < 2; ++mk) {
        int row = mk * 32 + l31;
        short8 kf = *(const short8*)(Kc + row * 64 + (((2 * st + hh) ^ (row & 7)) * 8));
        sacc[mk] = __builtin_amdgcn_mfma_f32_32x32x16_bf16(kf, qf[st], sacc[mk], 0, 0, 0);
      }

    // lane-local row max
    float t8[8];
#pragma unroll
    for (int r = 0; r < 8; ++r)
      t8[r] = fmaxf(fmaxf(sacc[0][r], sacc[0][r + 8]), fmaxf(sacc[1][r], sacc[1][r + 8]));
    float t4a = fmaxf(t8[0], t8[4]), t4b = fmaxf(t8[1], t8[5]);
    float t4c = fmaxf(t8[2], t8[6]), t4d = fmaxf(t8[3], t8[7]);
    float mloc = fmaxf(fmaxf(t4a, t4b), fmaxf(t4c, t4d));
    float m2 = fmaxf(mloc, __shfl_xor(mloc, 32));

    const int skip = __all(m2 <= M + 8.f);
    if (!skip) {
      float mnew = fmaxf(M, m2);
      float alpha = exp2f(M - mnew);
      M = mnew;
#pragma unroll
      for (int r = 0; r < 16; ++r) {
        int srcl = (r & 3) + 8 * (r >> 2) + hh * 4;
        float ar = __shfl(alpha, srcl);
        Oacc[0][r] *= ar;
        Oacc[1][r] *= ar;
        OaccL[r] *= ar;
      }
    }
#pragma unroll
    for (int mk = 0; mk < 2; ++mk)
#pragma unroll
      for (int r = 0; r < 16; ++r) sacc[mk][r] = exp2f(sacc[mk][r] - M);

    unsigned wpk[2][4][2];
#pragma unroll
    for (int mk = 0; mk < 2; ++mk)
#pragma unroll
      for (int c = 0; c < 4; ++c) {
        wpk[mk][c][0] = cvtpk(sacc[mk][4 * c + 0], sacc[mk][4 * c + 1]);
        wpk[mk][c][1] = cvtpk(sacc[mk][4 * c + 2], sacc[mk][4 * c + 3]);
      }

    const unsigned short* Vc = Vt[cur];
#pragma unroll
    for (int kk = 0; kk < 4; ++kk) {
      const int e = kk & 1, mk = kk >> 1;
      unsigned a0 = wpk[mk][2 * e][0], b0 = wpk[mk][2 * e + 1][0];
      unsigned a1 = wpk[mk][2 * e][1], b1 = wpk[mk][2 * e + 1][1];
      asm("v_permlane32_swap_b32 %0, %1" : "+v"(a0), "+v"(b0));
      asm("v_permlane32_swap_b32 %0, %1" : "+v"(a1), "+v"(b1));
      short8 pa = pack4(a0, a1, b0, b1);
#pragma unroll
      for (int nd = 0; nd < 2; ++nd) {
        int row = nd * 32 + l31;
        short8 vf = *(const short8*)(Vc + row * 64 + (((2 * kk + hh) ^ (row & 7)) * 8));
        Oacc[nd] = __builtin_amdgcn_mfma_f32_32x32x16_bf16(pa, vf, Oacc[nd], 0, 0, 0);
      }
      OaccL = __builtin_amdgcn_mfma_f32_32x32x16_bf16(pa, ones, OaccL, 0, 0, 0);
    }

    sched_fence();
    ASM_VMCNT(4);                  // tile jt+1 landed; jt+2 still in flight
    __builtin_amdgcn_s_barrier();
    sched_fence();
    cur = (cur == 2) ? 0 : cur + 1;
  }

  // epilogue: drain wrap-staged stragglers, then reuse Ks[0..1] as O-stage
  ASM_VMCNT(0);
  __syncthreads();
  unsigned short* Obuf = &Ks[0][0];  // 128x64 bf16 = 16KB
  float linv[16];
#pragma unroll
  for (int r = 0; r < 16; ++r) linv[r] = 1.f / OaccL[r];
#pragma unroll
  for (int nd = 0; nd < 2; ++nd)
#pragma unroll
    for (int r = 0; r < 16; ++r) {
      int q = wq + (r & 3) + 8 * (r >> 2) + hh * 4;
      int d = nd * 32 + l31;
      Obuf[q * 64 + (((d >> 3) ^ (q & 7)) * 8) + (d & 7)] = f2bf(Oacc[nd][r] * linv[r]);
    }
  __syncthreads();
#pragma unroll
  for (int i = 0; i < 4; ++i) {
    int c = tid + i * 256;
    int row = c >> 3, pj = c & 7;
    uint4 v = *(const uint4*)(Obuf + row * 64 + ((pj ^ (row & 7)) * 8));
    *(uint4*)(Ctx + ((size_t)(b * 2048 + qt * 128 + row)) * 1024 + (hb & 15) * 64 + pj * 8) = v;
  }
}

// ---------------- launch ----------------
extern "C" void kernel_launch(void* const* d_in, const int* in_sizes, int n_in,
                              void* d_out, int out_size, void* d_ws, size_t ws_size,
                              hipStream_t stream) {
  const float* query = (const float*)d_in[0];
  const float* key_  = (const float*)d_in[1];
  const float* value = (const float*)d_in[2];
  const float* Wq = (const float*)d_in[3];
  const float* bq = (const float*)d_in[4];
  const float* Wk = (const float*)d_in[5];
  const float* bk = (const float*)d_in[6];
  const float* Wv = (const float*)d_in[7];
  const float* bv = (const float*)d_in[8];
  const float* Wo = (const float*)d_in[9];
  const float* bo = (const float*)d_in[10];

  char* w = (char*)d_ws;
  unsigned short* Qp  = (unsigned short*)w; w += (size_t)8192 * 1024 * 2;  // [B,H,S,64]
  unsigned short* Kp  = (unsigned short*)w; w += (size_t)8192 * 1024 * 2;  // [B,H,S,64]
  unsigned short* VTp = (unsigned short*)w; w += (size_t)8192 * 1024 * 2;  // [B,H,64,S]
  unsigned short* Ctx = (unsigned short*)w; w += (size_t)8192 * 1024 * 2;  // [B,S,1024]

  qkv_gemm<<<dim3(8, 64, 3), 256, 0, stream>>>(query, key_, value, Wq, Wk, Wv,
                                               bq, bk, bv, Qp, Kp, VTp);

  attn_kernel<<<dim3(16, 16, 4), 256, 0, stream>>>(Qp, Kp, VTp, Ctx);

  gemm_o<<<dim3(8, 64), 256, 0, stream>>>(Ctx, Wo, bo, (float*)d_out);
}

// Round 8
// 378.582 us; speedup vs baseline: 1.1740x; 1.1740x over previous
//
#include <hip/hip_runtime.h>
#include <stdint.h>

typedef __attribute__((ext_vector_type(8))) short short8;     // 8 x bf16 MFMA operand
typedef __attribute__((ext_vector_type(4))) float floatx4;    // 16x16 MFMA accumulator
typedef __attribute__((ext_vector_type(16))) float floatx16;  // 32x32 MFMA accumulator

#define DEV __device__ __forceinline__

DEV unsigned short f2bf(float x) {  // fp32 -> bf16 RNE (epilogue-only)
  unsigned u = __float_as_uint(x);
  u += 0x7fffu + ((u >> 16) & 1u);
  return (unsigned short)(u >> 16);
}

// pack two fp32 -> two bf16 (round-half-up) in 3 VALU: 2 adds + v_perm
DEV unsigned pkbf(float hi, float lo) {
  return __builtin_amdgcn_perm(__float_as_uint(hi) + 0x8000u,
                               __float_as_uint(lo) + 0x8000u, 0x07060302u);
}

// single-instruction pack: dst = {lo16: bf16(a), hi16: bf16(b)} (RNE)
DEV unsigned cvtpk(float a, float b) {
  unsigned r;
  asm("v_cvt_pk_bf16_f32 %0, %1, %2" : "=v"(r) : "v"(a), "v"(b));
  return r;
}

DEV short8 pack4(unsigned a0, unsigned a1, unsigned b0, unsigned b1) {
  union { unsigned u[4]; short8 s; } t;
  t.u[0] = a0; t.u[1] = a1; t.u[2] = b0; t.u[3] = b1;
  return t.s;
}

DEV void load_lds16(const unsigned short* g, unsigned short* l) {
  __builtin_amdgcn_global_load_lds(
      (const __attribute__((address_space(1))) void*)g,
      (__attribute__((address_space(3))) void*)l, 16, 0, 0);
}

#define ASM_VMCNT(n) asm volatile("s_waitcnt vmcnt(" #n ")" ::: "memory")
DEV void sched_fence() { __builtin_amdgcn_sched_barrier(0); }

// GEMM LDS fragment read, chunk-swizzled: LDS slot s of row holds global chunk s^sw(row),
// sw(row) = (row>>1)&3. Read of chunk `quad` -> slot quad^sw. 16 lanes x b128 = exactly
// 2-way bank aliasing (free, m136) instead of ~8-way.
DEV short8 fragld(const unsigned short* buf, int row, int quad) {
  return *(const short8*)(buf + row * 32 + ((quad ^ ((row >> 1) & 3)) * 8));
}

// ---------------- one-shot fp32 -> bf16 of all 7 tensors ----------------
__global__ void cvt_all(const float* __restrict__ Wq, const float* __restrict__ Wk,
                        const float* __restrict__ Wv, const float* __restrict__ Wo,
                        const float* __restrict__ Xq, const float* __restrict__ Xk,
                        const float* __restrict__ Xv,
                        unsigned short* __restrict__ Wb, unsigned short* __restrict__ XqB,
                        unsigned short* __restrict__ XkB, unsigned short* __restrict__ XvB) {
  int bid = blockIdx.x;
  const float* src;
  unsigned short* dst;
  int off;
  if (bid < 4096) {
    int sel = bid >> 10;
    src = sel == 0 ? Wq : sel == 1 ? Wk : sel == 2 ? Wv : Wo;
    dst = Wb + (size_t)sel * 1048576;
    off = bid & 1023;
  } else {
    bid -= 4096;
    int sel = bid >> 13;
    src = sel == 0 ? Xq : sel == 1 ? Xk : Xv;
    dst = sel == 0 ? XqB : sel == 1 ? XkB : XvB;
    off = bid & 8191;
  }
  int i = (off * 256 + threadIdx.x) * 4;
  float4 v = *(const float4*)(src + i);
  uint2 o;
  o.x = pkbf(v.y, v.x);
  o.y = pkbf(v.w, v.z);
  *(uint2*)(dst + i) = o;
}

// ---------------- fused QKV projection (R5 structure + chunk swizzle), grid (8,64,3) --------
#define SCQ (0.125f * 1.44269504089f)
__global__ __launch_bounds__(256, 3) void qkv_gemm(
    const unsigned short* __restrict__ XqB, const unsigned short* __restrict__ XkB,
    const unsigned short* __restrict__ XvB,
    const unsigned short* __restrict__ Wb,
    const float* __restrict__ bq, const float* __restrict__ bk, const float* __restrict__ bv,
    unsigned short* __restrict__ Qp, unsigned short* __restrict__ Kp,
    unsigned short* __restrict__ VTp) {
  __shared__ alignas(16) unsigned short Xs[3][128 * 32];
  __shared__ alignas(16) unsigned short Ws[3][128 * 32];
  const int z = blockIdx.z;
  const unsigned short* X = z == 0 ? XqB : z == 1 ? XkB : XvB;
  const unsigned short* W = Wb + (size_t)z * 1048576;
  const float* bias = z == 0 ? bq : z == 1 ? bk : bv;

  const int tid = threadIdx.x;
  const int lane = tid & 63, wave = tid >> 6;
  const int lcol = lane & 15, quad = lane >> 4;
  // XCD L2-locality remap (R3): xcd owns a contiguous 8-block s-span
  const int n2 = blockIdx.x + 8 * blockIdx.y;
  const int xcd = n2 & 7, ii = n2 >> 3;
  const int wo = (ii >> 3) * 128;
  const int xo = (xcd * 8 + (ii & 7)) * 128;
  const int wm = (wave & 1) * 64;
  const int wn = (wave >> 1) * 64;

  floatx4 acc[4][4];
  for (int mi = 0; mi < 4; ++mi)
    for (int ni = 0; ni < 4; ++ni)
      for (int r = 0; r < 4; ++r) acc[mi][ni][r] = 0.f;

  // staging: LDS dest linear (global_load_lds requirement); source chunk pre-swizzled
  auto stage = [&](int kt, int buf) {
    const int k0 = kt * 32;
#pragma unroll
    for (int l = 0; l < 2; ++l) {
      int c = tid + l * 256;
      int row = c >> 2, ch = c & 3;
      int sch = ch ^ ((row >> 1) & 3);
      load_lds16(W + (size_t)(wo + row) * 1024 + k0 + sch * 8, Ws[buf] + c * 8);
      load_lds16(X + (size_t)(xo + row) * 1024 + k0 + sch * 8, Xs[buf] + c * 8);
    }
  };

  stage(0, 0);
  stage(1, 1);
  int cur = 0;
  for (int kt = 0; kt < 32; ++kt) {
    sched_fence();
    ASM_VMCNT(4);                    // tile kt landed; tile kt+1 still in flight
    __builtin_amdgcn_s_barrier();
    sched_fence();
    int nb = cur + 2; if (nb >= 3) nb -= 3;
    stage((kt + 2) & 31, nb);        // wrap-issue keeps vmcnt count uniform at tail
    const unsigned short* Ab = (z < 2) ? Ws[cur] : Xs[cur];
    const unsigned short* Bb = (z < 2) ? Xs[cur] : Ws[cur];
    short8 af[4], bfr[4];
#pragma unroll
    for (int mi = 0; mi < 4; ++mi) af[mi] = fragld(Ab, wm + mi * 16 + lcol, quad);
#pragma unroll
    for (int ni = 0; ni < 4; ++ni) bfr[ni] = fragld(Bb, wn + ni * 16 + lcol, quad);
#pragma unroll
    for (int mi = 0; mi < 4; ++mi)
#pragma unroll
      for (int ni = 0; ni < 4; ++ni)
        acc[mi][ni] = __builtin_amdgcn_mfma_f32_16x16x32_bf16(af[mi], bfr[ni], acc[mi][ni], 0, 0, 0);
    cur = (cur == 2) ? 0 : cur + 1;
  }

  if (z < 2) {  // lane: d = wo+wm+mi*16+quad*4 (consecutive), s = xo+wn+ni*16+lcol
    unsigned short* Out = z == 0 ? Qp : Kp;
    const float scl = z == 0 ? SCQ : 1.f;
#pragma unroll
    for (int mi = 0; mi < 4; ++mi) {
      int dbase = wo + wm + mi * 16 + quad * 4;
      float4 bv4 = *(const float4*)(bias + dbase);
      int h = dbase >> 6, dk = dbase & 63;
#pragma unroll
      for (int ni = 0; ni < 4; ++ni) {
        int sg = xo + wn + ni * 16 + lcol;
        int bb = sg >> 11, ss = sg & 2047;
        uint2 o;
        o.x = pkbf((acc[mi][ni][1] + bv4.y) * scl, (acc[mi][ni][0] + bv4.x) * scl);
        o.y = pkbf((acc[mi][ni][3] + bv4.w) * scl, (acc[mi][ni][2] + bv4.z) * scl);
        *(uint2*)(Out + ((size_t)(bb * 16 + h) * 2048 + ss) * 64 + dk) = o;
      }
    }
  } else {  // lane: s = xo+wm+mi*16+quad*4 (consecutive), d = wo+wn+ni*16+lcol -> V^T
#pragma unroll
    for (int ni = 0; ni < 4; ++ni) {
      int dg = wo + wn + ni * 16 + lcol;
      float bvx = bias[dg];
      int h = dg >> 6, dk = dg & 63;
#pragma unroll
      for (int mi = 0; mi < 4; ++mi) {
        int sbase = xo + wm + mi * 16 + quad * 4;
        int bb = sbase >> 11, ss = sbase & 2047;
        uint2 o;
        o.x = pkbf(acc[mi][ni][1] + bvx, acc[mi][ni][0] + bvx);
        o.y = pkbf(acc[mi][ni][3] + bvx, acc[mi][ni][2] + bvx);
        *(uint2*)(VTp + ((size_t)(bb * 16 + h) * 64 + dk) * 2048 + ss) = o;
      }
    }
  }
}

// ---------------- final O-projection: fp32 out, depth-2 counted-vmcnt + chunk swizzle -------
__global__ __launch_bounds__(256, 3) void gemm_o(
    const unsigned short* __restrict__ A, const unsigned short* __restrict__ Bw,
    const float* __restrict__ bias, float* __restrict__ Out) {
  __shared__ alignas(16) unsigned short Cs[3][128 * 32];
  __shared__ alignas(16) unsigned short Wos[3][128 * 32];
  const int tid = threadIdx.x;
  const int lane = tid & 63, wave = tid >> 6;
  const int lcol = lane & 15, quad = lane >> 4;
  const int n2 = blockIdx.x + 8 * blockIdx.y;
  const int xcd = n2 & 7, ii = n2 >> 3;
  const int co = (ii >> 3) * 128;
  const int so = (xcd * 8 + (ii & 7)) * 128;
  const int wm = (wave & 1) * 64;
  const int wn = (wave >> 1) * 64;

  floatx4 acc[4][4];
  for (int mi = 0; mi < 4; ++mi)
    for (int ni = 0; ni < 4; ++ni)
      for (int r = 0; r < 4; ++r) acc[mi][ni][r] = 0.f;

  auto stage = [&](int kt, int buf) {
    const int k0 = kt * 32;
#pragma unroll
    for (int l = 0; l < 2; ++l) {
      int c = tid + l * 256;
      int row = c >> 2, ch = c & 3;
      int sch = ch ^ ((row >> 1) & 3);
      load_lds16(Bw + (size_t)(co + row) * 1024 + k0 + sch * 8, Wos[buf] + c * 8);
      load_lds16(A  + (size_t)(so + row) * 1024 + k0 + sch * 8, Cs[buf] + c * 8);
    }
  };

  stage(0, 0);
  stage(1, 1);
  int cur = 0;
  for (int kt = 0; kt < 32; ++kt) {
    sched_fence();
    ASM_VMCNT(4);
    __builtin_amdgcn_s_barrier();
    sched_fence();
    int nb = cur + 2; if (nb >= 3) nb -= 3;
    stage((kt + 2) & 31, nb);
    short8 af[4], bfr[4];
#pragma unroll
    for (int mi = 0; mi < 4; ++mi) af[mi] = fragld(Wos[cur], wm + mi * 16 + lcol, quad);
#pragma unroll
    for (int ni = 0; ni < 4; ++ni) bfr[ni] = fragld(Cs[cur], wn + ni * 16 + lcol, quad);
#pragma unroll
    for (int mi = 0; mi < 4; ++mi)
#pragma unroll
      for (int ni = 0; ni < 4; ++ni)
        acc[mi][ni] = __builtin_amdgcn_mfma_f32_16x16x32_bf16(af[mi], bfr[ni], acc[mi][ni], 0, 0, 0);
    cur = (cur == 2) ? 0 : cur + 1;
  }
#pragma unroll
  for (int mi = 0; mi < 4; ++mi) {
    int cb = co + wm + mi * 16 + quad * 4;  // 4 consecutive output cols
    float4 bv4 = *(const float4*)(bias + cb);
#pragma unroll
    for (int ni = 0; ni < 4; ++ni) {
      int sg = so + wn + ni * 16 + lcol;
      float4 o;
      o.x = acc[mi][ni][0] + bv4.x;
      o.y = acc[mi][ni][1] + bv4.y;
      o.z = acc[mi][ni][2] + bv4.z;
      o.w = acc[mi][ni][3] + bv4.w;
      *(float4*)(Out + (size_t)sg * 1024 + cb) = o;
    }
  }
}

// ---------------- flash attention, 32x32 MFMA, in-register P (R5 exact, measured 137.4) -----
__global__ __launch_bounds__(256, 3) void attn_kernel(
    const unsigned short* __restrict__ Qp, const unsigned short* __restrict__ Kp,
    const unsigned short* __restrict__ VTp, unsigned short* __restrict__ Ctx) {
  __shared__ alignas(16) unsigned short Ks[3][64 * 64];  // K tiles (24KB); reused as O-stage
  __shared__ alignas(16) unsigned short Vt[3][64 * 64];  // V^T tiles (24KB)

  const int tid = threadIdx.x;
  const int lane = tid & 63, wave = tid >> 6;
  const int l31 = lane & 31, hh = lane >> 5;
  const int wq = wave * 32;
  const int n = blockIdx.x + 16 * (blockIdx.y + 16 * blockIdx.z);
  const int xcd = n & 7, ii = n >> 3;
  const int hb = xcd * 8 + (ii & 7);  // = b*16 + h
  const int qt = ii >> 3;
  const size_t bh = (size_t)hb * 2048 * 64;
  const int b = hb >> 4;
  const unsigned short* Qb = Qp + bh + (size_t)qt * 128 * 64;
  const unsigned short* Kb = Kp + bh;
  const unsigned short* VTb = VTp + bh;

  short8 qf[4];
#pragma unroll
  for (int st = 0; st < 4; ++st)
    qf[st] = *(const short8*)(Qb + (wq + l31) * 64 + st * 16 + hh * 8);

  auto stageK = [&](int jt, int buf) {
#pragma unroll
    for (int i = 0; i < 2; ++i) {
      int p = tid + i * 256;
      int kr = p >> 3, kj = p & 7;
      load_lds16(Kb + (size_t)jt * 4096 + kr * 64 + ((kj ^ (kr & 7)) * 8), Ks[buf] + p * 8);
    }
  };
  auto stageV = [&](int jt, int buf) {
#pragma unroll
    for (int i = 0; i < 2; ++i) {
      int p = tid + i * 256;
      int vr = p >> 3, vj = p & 7;
      load_lds16(VTb + (size_t)vr * 2048 + jt * 64 + ((vj ^ (vr & 7)) * 8), Vt[buf] + p * 8);
    }
  };

  stageK(0, 0); stageV(0, 0);
  stageK(1, 1); stageV(1, 1);
  __syncthreads();  // tiles 0,1 resident

  short8 ones;
#pragma unroll
  for (int j = 0; j < 8; ++j) ones[j] = (short)0x3f80;

  float M = -1e30f;  // per-lane: q = wq + l31 (identical in both halves)
  floatx16 Oacc[2], OaccL;
#pragma unroll
  for (int r = 0; r < 16; ++r) { Oacc[0][r] = 0.f; Oacc[1][r] = 0.f; OaccL[r] = 0.f; }

  int cur = 0;
  for (int jt = 0; jt < 32; ++jt) {
    int nb = cur + 2; if (nb >= 3) nb -= 3;
    const int jn = (jt + 2) & 31;  // wrap-issue keeps vmcnt uniform (epilogue drains)
    stageK(jn, nb);
    stageV(jn, nb);

    // S^T[k=64][q=32]: 2 mk-blocks x 4 d-steps of 32x32x16
    const unsigned short* Kc = Ks[cur];
    floatx16 sacc[2];
#pragma unroll
    for (int r = 0; r < 16; ++r) { sacc[0][r] = 0.f; sacc[1][r] = 0.f; }
#pragma unroll
    for (int st = 0; st < 4; ++st)
#pragma unroll
      for (int mk = 0; mk < 2; ++mk) {
        int row = mk * 32 + l31;
        short8 kf = *(const short8*)(Kc + row * 64 + (((2 * st + hh) ^ (row & 7)) * 8));
        sacc[mk] = __builtin_amdgcn_mfma_f32_32x32x16_bf16(kf, qf[st], sacc[mk], 0, 0, 0);
      }

    // lane-local row max (lane holds 32 of 64 k for its q; other half in lane^32)
    float t8[8];
#pragma unroll
    for (int r = 0; r < 8; ++r)
      t8[r] = fmaxf(fmaxf(sacc[0][r], sacc[0][r + 8]), fmaxf(sacc[1][r], sacc[1][r + 8]));
    float t4a = fmaxf(t8[0], t8[4]), t4b = fmaxf(t8[1], t8[5]);
    float t4c = fmaxf(t8[2], t8[6]), t4d = fmaxf(t8[3], t8[7]);
    float mloc = fmaxf(fmaxf(t4a, t4b), fmaxf(t4c, t4d));
    float m2 = fmaxf(mloc, __shfl_xor(mloc, 32));

    const int skip = __all(m2 <= M + 8.f);
    if (!skip) {
      float mnew = fmaxf(M, m2);
      float alpha = exp2f(M - mnew);
      M = mnew;
#pragma unroll
      for (int r = 0; r < 16; ++r) {
        int srcl = (r & 3) + 8 * (r >> 2) + hh * 4;
        float ar = __shfl(alpha, srcl);
        Oacc[0][r] *= ar;
        Oacc[1][r] *= ar;
        OaccL[r] *= ar;
      }
    }
#pragma unroll
    for (int mk = 0; mk < 2; ++mk)
#pragma unroll
      for (int r = 0; r < 16; ++r) sacc[mk][r] = exp2f(sacc[mk][r] - M);

    unsigned wpk[2][4][2];
#pragma unroll
    for (int mk = 0; mk < 2; ++mk)
#pragma unroll
      for (int c = 0; c < 4; ++c) {
        wpk[mk][c][0] = cvtpk(sacc[mk][4 * c + 0], sacc[mk][4 * c + 1]);
        wpk[mk][c][1] = cvtpk(sacc[mk][4 * c + 2], sacc[mk][4 * c + 3]);
      }

    const unsigned short* Vc = Vt[cur];
#pragma unroll
    for (int kk = 0; kk < 4; ++kk) {
      const int e = kk & 1, mk = kk >> 1;
      unsigned a0 = wpk[mk][2 * e][0], b0 = wpk[mk][2 * e + 1][0];
      unsigned a1 = wpk[mk][2 * e][1], b1 = wpk[mk][2 * e + 1][1];
      asm("v_permlane32_swap_b32 %0, %1" : "+v"(a0), "+v"(b0));
      asm("v_permlane32_swap_b32 %0, %1" : "+v"(a1), "+v"(b1));
      short8 pa = pack4(a0, a1, b0, b1);
#pragma unroll
      for (int nd = 0; nd < 2; ++nd) {
        int row = nd * 32 + l31;
        short8 vf = *(const short8*)(Vc + row * 64 + (((2 * kk + hh) ^ (row & 7)) * 8));
        Oacc[nd] = __builtin_amdgcn_mfma_f32_32x32x16_bf16(pa, vf, Oacc[nd], 0, 0, 0);
      }
      OaccL = __builtin_amdgcn_mfma_f32_32x32x16_bf16(pa, ones, OaccL, 0, 0, 0);
    }

    sched_fence();
    ASM_VMCNT(4);                  // tile jt+1 landed; jt+2 still in flight
    __builtin_amdgcn_s_barrier();
    sched_fence();
    cur = (cur == 2) ? 0 : cur + 1;
  }

  // epilogue: drain wrap-staged stragglers, then reuse Ks[0..1] as O-stage
  ASM_VMCNT(0);
  __syncthreads();
  unsigned short* Obuf = &Ks[0][0];  // 128x64 bf16 = 16KB
  float linv[16];
#pragma unroll
  for (int r = 0; r < 16; ++r) linv[r] = 1.f / OaccL[r];
#pragma unroll
  for (int nd = 0; nd < 2; ++nd)
#pragma unroll
    for (int r = 0; r < 16; ++r) {
      int q = wq + (r & 3) + 8 * (r >> 2) + hh * 4;
      int d = nd * 32 + l31;
      Obuf[q * 64 + (((d >> 3) ^ (q & 7)) * 8) + (d & 7)] = f2bf(Oacc[nd][r] * linv[r]);
    }
  __syncthreads();
#pragma unroll
  for (int i = 0; i < 4; ++i) {
    int c = tid + i * 256;
    int row = c >> 3, pj = c & 7;
    uint4 v = *(const uint4*)(Obuf + row * 64 + ((pj ^ (row & 7)) * 8));
    *(uint4*)(Ctx + ((size_t)(b * 2048 + qt * 128 + row)) * 1024 + (hb & 15) * 64 + pj * 8) = v;
  }
}

// ---------------- launch ----------------
extern "C" void kernel_launch(void* const* d_in, const int* in_sizes, int n_in,
                              void* d_out, int out_size, void* d_ws, size_t ws_size,
                              hipStream_t stream) {
  const float* query = (const float*)d_in[0];
  const float* key_  = (const float*)d_in[1];
  const float* value = (const float*)d_in[2];
  const float* Wq = (const float*)d_in[3];
  const float* bq = (const float*)d_in[4];
  const float* Wk = (const float*)d_in[5];
  const float* bk = (const float*)d_in[6];
  const float* Wv = (const float*)d_in[7];
  const float* bv = (const float*)d_in[8];
  const float* Wo = (const float*)d_in[9];
  const float* bo = (const float*)d_in[10];

  char* w = (char*)d_ws;
  unsigned short* Wb  = (unsigned short*)w; w += (size_t)4 * 1024 * 1024 * 2;  // Wq,Wk,Wv,Wo bf16
  unsigned short* Qp  = (unsigned short*)w; w += (size_t)8192 * 1024 * 2;      // [B,H,S,64]
  unsigned short* Kp  = (unsigned short*)w; w += (size_t)8192 * 1024 * 2;      // [B,H,S,64]
  unsigned short* VTp = (unsigned short*)w; w += (size_t)8192 * 1024 * 2;      // [B,H,64,S]
  unsigned short* Ctx = (unsigned short*)w; w += (size_t)8192 * 1024 * 2;      // [B,S,1024]

  // bf16 activations: query/key park in d_out (32 MB, dead until gemm_o);
  // value parks in the Ctx slot (dead once qkv_gemm completes, before attn writes Ctx).
  unsigned short* XqB = (unsigned short*)d_out;
  unsigned short* XkB = (unsigned short*)d_out + (size_t)8192 * 1024;
  unsigned short* XvB = Ctx;

  cvt_all<<<28672, 256, 0, stream>>>(Wq, Wk, Wv, Wo, query, key_, value,
                                     Wb, XqB, XkB, XvB);

  qkv_gemm<<<dim3(8, 64, 3), 256, 0, stream>>>(XqB, XkB, XvB, Wb,
                                               bq, bk, bv, Qp, Kp, VTp);

  attn_kernel<<<dim3(16, 16, 4), 256, 0, stream>>>(Qp, Kp, VTp, Ctx);

  gemm_o<<<dim3(8, 64), 256, 0, stream>>>(Ctx, Wb + (size_t)3 * 1048576, bo, (float*)d_out);
}